// Round 14
// baseline (240.335 us; speedup 1.0000x reference)
//
#include <hip/hip_runtime.h>
#include <hip/hip_bf16.h>
#include <hip/hip_fp16.h>

static constexpr int NN = 1000000;   // nodes
static constexpr int NE = 5000000;   // edges
static constexpr int NG = 4096;      // graphs
static constexpr int BIN_SH = 8;                      // 256 nodes per bin
static constexpr int BIN_SZ = 1 << BIN_SH;            // 256
static constexpr int NB = (NN + BIN_SZ - 1) >> BIN_SH;   // 3907 (last bin = 64 nodes, %64==0)
static constexpr int EPB = 16384;                     // edges per block for binning passes
static constexpr int BIN_BLOCKS = (NE + EPB - 1) / EPB;  // 306
static constexpr int CHUNK = 512;                     // edges per LDS chunk (18 KB -> 8 blocks/CU)

// transform(x) == tanh(x) for finite x. Clamp-free: 1 - 2/(e^{2x}+1) is exact
// at the extremes (e=inf -> 1, e=0 -> -1), no NaN for finite x.
__device__ __forceinline__ float fast_tanh(float x) {
    float e = __expf(2.0f * x);
    return 1.0f - 2.0f * __fdividef(1.0f, e + 1.0f);
}

// ---- Pass 0: pack x into fp16x4 (8 B/node, 8 MB total) for the edge gather ----
__global__ __launch_bounds__(256) void x2h_k(
    const float* __restrict__ x, __half* __restrict__ xh)   // [NN,4]
{
    int i = blockIdx.x * 256 + threadIdx.x;
    if (i >= NN) return;
    union { __half2 h2[2]; uint2 u; } o;
    o.h2[0] = __floats2half2_rn(x[3 * i + 0], x[3 * i + 1]);
    o.h2[1] = __floats2half2_rn(x[3 * i + 2], 0.0f);
    *reinterpret_cast<uint2*>(xh + 4 * (size_t)i) = o.u;
}

// ---- Pass 1: per-bin edge counts (LDS histogram, 1 global atomic per block-bin) ----
__global__ __launch_bounds__(256) void bin_hist_k(
    const int* __restrict__ row, int* __restrict__ binCount)
{
    __shared__ int hist[NB];          // 15.6 KB
    for (int i = threadIdx.x; i < NB; i += 256) hist[i] = 0;
    __syncthreads();
    int base = blockIdx.x * EPB;
#pragma unroll 4
    for (int k = 0; k < EPB / 256; ++k) {
        int e = base + k * 256 + threadIdx.x;
        if (e < NE) atomicAdd(&hist[row[e] >> BIN_SH], 1);
    }
    __syncthreads();
    for (int i = threadIdx.x; i < NB; i += 256) {
        int c = hist[i];
        if (c) atomicAdd(&binCount[i], c);
    }
}

// ---- Pass 2: exclusive scan of binCount (NB<=4096) -> binStart, binCursor ----
__global__ __launch_bounds__(1024) void bin_scan_k(
    const int* __restrict__ binCount, int* __restrict__ binStart, int* __restrict__ binCursor)
{
    __shared__ int s[1024];
    int t = threadIdx.x;
    int base = t * 4;
    int v[4];
    int tv = 0;
#pragma unroll
    for (int k = 0; k < 4; ++k) {
        v[k] = (base + k < NB) ? binCount[base + k] : 0;
        tv += v[k];
    }
    s[t] = tv;
    __syncthreads();
    for (int off = 1; off < 1024; off <<= 1) {
        int u = (t >= off) ? s[t - off] : 0;
        __syncthreads();
        s[t] += u;
        __syncthreads();
    }
    int ex = s[t] - tv;
#pragma unroll
    for (int k = 0; k < 4; ++k) {
        if (base + k < NB) { binStart[base + k] = ex; binCursor[base + k] = ex; }
        ex += v[k];
    }
    if (t == 0) binStart[NB] = NE;
}

// ---- Pass 3: scatter packed (rl, col) into CSR-TIGHT bin-grouped order ----
// Dense 20 MB destination: same-bin edges from a block land contiguously and
// bins are adjacent -> L2 absorbs partial lines (proven ~45us, WRITE ~25MB).
__global__ __launch_bounds__(256) void bin_scatter_k(
    const int* __restrict__ row, const int* __restrict__ col,
    int* __restrict__ binCursor, unsigned int* __restrict__ pack)
{
    __shared__ int hist[NB];
    for (int i = threadIdx.x; i < NB; i += 256) hist[i] = 0;
    __syncthreads();
    int base = blockIdx.x * EPB;
#pragma unroll 4
    for (int k = 0; k < EPB / 256; ++k) {
        int e = base + k * 256 + threadIdx.x;
        if (e < NE) atomicAdd(&hist[row[e] >> BIN_SH], 1);
    }
    __syncthreads();
    // hist[bin] becomes this block's ABSOLUTE write cursor (CSR offsets)
    for (int i = threadIdx.x; i < NB; i += 256) {
        int c = hist[i];
        hist[i] = c ? atomicAdd(&binCursor[i], c) : 0;
    }
    __syncthreads();
#pragma unroll 4
    for (int k = 0; k < EPB / 256; ++k) {
        int e = base + k * 256 + threadIdx.x;
        if (e >= NE) continue;
        int r = row[e];
        int c = col[e];
        int pos = atomicAdd(&hist[r >> BIN_SH], 1);
        pack[pos] = ((unsigned int)(r & (BIN_SZ - 1)) << 20) | (unsigned int)c;
    }
}

// ---- Pass 4: per-bin chunked pipeline (8 blocks/CU for gather latency hiding) ----
// stride-256 pack read -> gather xh[col] (8B, L2/L3) -> edge-parallel MLP1+tanh
// -> fp16 payload counting-sort through LDS (wave-shuffle scan) -> owner pk_add.
__global__ __launch_bounds__(256) void bucket_agg_k(
    const unsigned int* __restrict__ pack,
    const int* __restrict__ binStart,
    const __half* __restrict__ xh,  // [NN,4]
    const int* __restrict__ batch,
    const float* __restrict__ w1,   // [3,16]
    const float* __restrict__ b1,   // [16]
    const float* __restrict__ w2,   // [16,16]
    const float* __restrict__ b2,   // [16]
    float* __restrict__ h_sum,      // [NG,16]
    unsigned int* __restrict__ h_max, // [NG,16] monotone-encoded
    int* __restrict__ cnt)          // [NG]
{
    __shared__ uint4 pay[CHUNK * 2];   // 16 KB sorted h1-payloads (16 halfs/edge)
    __shared__ int scnt[BIN_SZ];       // hist -> cursor
    __shared__ int sstart[BIN_SZ];     // exclusive starts
    __shared__ int wsum[4];            // per-wave scan sums

    int tid = threadIdx.x;
    int lane = tid & 63, wid = tid >> 6;
    int b = blockIdx.x;
    int nodeBase = b << BIN_SH;
    int nNodes = min(BIN_SZ, NN - nodeBase);   // 256, or 64 for last bin (%64==0)
    int es = binStart[b], ee = binStart[b + 1];

    __half2 acc8[8];
#pragma unroll
    for (int q = 0; q < 8; ++q) acc8[q] = __half2half2(__float2half(0.0f));
    int dg = 0;

    for (int cs = es; cs < ee; cs += CHUNK) {
        int m = min(CHUNK, ee - cs);
        scnt[tid] = 0;
        __syncthreads();                                   // B1

        // stride-256 loads: balanced across threads even in tail chunks
        uint2 gx[2];
        int rl2[2];
#pragma unroll
        for (int k = 0; k < 2; ++k) {
            int e = cs + k * 256 + tid;
            rl2[k] = -1;
            if (e < cs + m) {
                unsigned int p = pack[e];
                int c = (int)(p & 0xFFFFFu);
                rl2[k] = (int)(p >> 20);
                gx[k] = *reinterpret_cast<const uint2*>(xh + 4 * (size_t)c);
                atomicAdd(&scnt[rl2[k]], 1);   // no-return ds_add
            }
        }
        __syncthreads();                                   // B2

        // exclusive scan of scnt via wave shuffles
        int v = scnt[tid];
        int sc = v;
#pragma unroll
        for (int off = 1; off < 64; off <<= 1) {
            int u = __shfl_up(sc, off);
            if (lane >= off) sc += u;
        }
        if (lane == 63) wsum[wid] = sc;
        __syncthreads();                                   // B3
        int pre = 0;
#pragma unroll
        for (int w = 0; w < 4; ++w) pre += (w < wid) ? wsum[w] : 0;
        int ex = pre + sc - v;
        sstart[tid] = ex;
        scnt[tid] = ex;
        __syncthreads();                                   // B4

        // EDGE-PARALLEL MLP1 + tanh (balanced), then counting-sort scatter
#pragma unroll
        for (int k = 0; k < 2; ++k) {
            if (rl2[k] >= 0) {
                union { uint2 u; __half2 h2[2]; } xi;
                xi.u = gx[k];
                float2 x01 = __half22float2(xi.h2[0]);
                float x2v = __low2float(xi.h2[1]);
                union { __half2 h2[8]; uint4 u[2]; } o;
#pragma unroll
                for (int q = 0; q < 8; ++q) {
                    float va = fmaf(x2v, w1[32 + 2 * q], fmaf(x01.y, w1[16 + 2 * q],
                               fmaf(x01.x, w1[2 * q], b1[2 * q])));
                    float vb = fmaf(x2v, w1[33 + 2 * q], fmaf(x01.y, w1[17 + 2 * q],
                               fmaf(x01.x, w1[2 * q + 1], b1[2 * q + 1])));
                    o.h2[q] = __floats2half2_rn(fast_tanh(va), fast_tanh(vb));
                }
                int pos = atomicAdd(&scnt[rl2[k]], 1);   // returning ds_add_rtn
                pay[2 * pos + 0] = o.u[0];
                pay[2 * pos + 1] = o.u[1];
            }
        }
        __syncthreads();                                   // B5

        // owner accumulation: thread tid owns node tid; 8 pk_add_f16 per edge
        if (tid < nNodes) {
            int s0 = sstart[tid];
            int e0 = (tid < 255) ? sstart[tid + 1] : m;
            dg += e0 - s0;
            for (int e = s0; e < e0; ++e) {
                union { uint4 u; __half2 h2[4]; } ua, ub;
                ua.u = pay[2 * e + 0];
                ub.u = pay[2 * e + 1];
#pragma unroll
                for (int q = 0; q < 4; ++q) {
                    acc8[q] = __hadd2(acc8[q], ua.h2[q]);
                    acc8[4 + q] = __hadd2(acc8[4 + q], ub.h2[q]);
                }
            }
        }
        __syncthreads();                                   // B6
    }

    // node phase: normalize, MLP2, tanh, segmented wave reduction over sorted batch
    if (tid < nNodes) {                       // wave-uniform (nNodes % 64 == 0)
        float acc[16];
#pragma unroll
        for (int q = 0; q < 8; ++q) {
            float2 f = __half22float2(acc8[q]);
            acc[2 * q + 0] = f.x;
            acc[2 * q + 1] = f.y;
        }
        float inv = 1.0f / fmaxf((float)dg, 1.0f);
        float s[16];
#pragma unroll
        for (int j = 0; j < 16; ++j) s[j] = b2[j];
#pragma unroll
        for (int k = 0; k < 16; ++k) {
            float a = acc[k] * inv;
#pragma unroll
            for (int j = 0; j < 16; ++j) s[j] = fmaf(a, w2[16 * k + j], s[j]);
        }
        float m[16];
#pragma unroll
        for (int j = 0; j < 16; ++j) { s[j] = fast_tanh(s[j]); m[j] = s[j]; }

        int g = batch[nodeBase + tid];
        int gp = __shfl_up(g, 1);
        int head = (lane == 0) || (g != gp);
        unsigned long long hm = __ballot(head != 0);

        int f = head;
#pragma unroll
        for (int off = 1; off < 64; off <<= 1) {
            int fu = __shfl_up(f, off);
            bool take = (lane >= off) && (f == 0);
#pragma unroll
            for (int j = 0; j < 16; ++j) {
                float su = __shfl_up(s[j], off);
                float mu = __shfl_up(m[j], off);
                if (take) { s[j] += su; m[j] = fmaxf(m[j], mu); }
            }
            if (lane >= off) f |= fu;
        }

        int hnext = __shfl_down(head, 1);
        bool is_last = (lane == 63) || (hnext != 0);
        if (is_last) {
            unsigned long long below = hm & (~0ULL >> (63 - lane));
            int start = 63 - __clzll(below);
            int seglen = lane - start + 1;
#pragma unroll
            for (int j = 0; j < 16; ++j) {
                unsafeAtomicAdd(&h_sum[16 * g + j], s[j]);
                atomicMax(&h_max[16 * g + j], __float_as_uint(m[j] + 2.0f));
            }
            atomicAdd(&cnt[g], seglen);
        }
    }
}

// ---- Pass 5: head ----
__global__ __launch_bounds__(256) void out_k(
    const float* __restrict__ h_sum,
    const unsigned int* __restrict__ h_max,
    const int* __restrict__ cnt,
    const float* __restrict__ w3,   // [32]
    const float* __restrict__ b3,   // [1]
    float* __restrict__ out)        // [NG]
{
    int g = blockIdx.x * 256 + threadIdx.x;
    if (g >= NG) return;
    float invc = 1.0f / fmaxf((float)cnt[g], 1.0f);
    float acc = b3[0];
#pragma unroll
    for (int j = 0; j < 16; ++j) {
        float mean = h_sum[16 * g + j] * invc;
        unsigned int e = h_max[16 * g + j];
        float mx = (e == 0u) ? 0.0f : (__uint_as_float(e) - 2.0f);
        acc = fmaf(mean, w3[j], fmaf(mx, w3[16 + j], acc));
    }
    out[g] = 1.0f / (1.0f + __expf(-acc));
}

extern "C" void kernel_launch(void* const* d_in, const int* in_sizes, int n_in,
                              void* d_out, int out_size, void* d_ws, size_t ws_size,
                              hipStream_t stream)
{
    const float* x   = (const float*)d_in[0];
    const int*   ei  = (const int*)d_in[1];   // row = ei, col = ei + NE
    const int*   bat = (const int*)d_in[2];
    const float* w1  = (const float*)d_in[3];
    const float* b1  = (const float*)d_in[4];
    const float* w2  = (const float*)d_in[5];
    const float* b2  = (const float*)d_in[6];
    const float* w3  = (const float*)d_in[7];
    const float* b3  = (const float*)d_in[8];
    float* out = (float*)d_out;

    char* ws = (char*)d_ws;
    size_t off = 0;
    // --- zeroed region (one small memset, ~0.57 MB) ---
    int* binCount = (int*)(ws + off);          off += 16384;                 // NB ints, padded
    float* h_sum  = (float*)(ws + off);        off += (size_t)NG * 16 * 4;
    unsigned int* h_max = (unsigned int*)(ws + off); off += (size_t)NG * 16 * 4;
    int* cnt      = (int*)(ws + off);          off += (size_t)NG * 4;
    size_t zero_bytes = off;
    // --- non-zeroed scratch (total ~29 MB) ---
    int* binStart = (int*)(ws + off);          off += 16384;                 // NB+1 ints
    int* binCursor= (int*)(ws + off);          off += 16384;                 // NB ints
    unsigned int* pack = (unsigned int*)(ws + off); off += (size_t)NE * 4;   // 20 MB, dense
    __half* xh    = (__half*)(ws + off);       off += (size_t)NN * 4 * 2;    // 8 MB

    hipMemsetAsync(d_ws, 0, zero_bytes, stream);

    x2h_k<<<(NN + 255) / 256, 256, 0, stream>>>(x, xh);
    bin_hist_k<<<BIN_BLOCKS, 256, 0, stream>>>(ei, binCount);
    bin_scan_k<<<1, 1024, 0, stream>>>(binCount, binStart, binCursor);
    bin_scatter_k<<<BIN_BLOCKS, 256, 0, stream>>>(ei, ei + NE, binCursor, pack);
    bucket_agg_k<<<NB, 256, 0, stream>>>(pack, binStart, xh, bat,
                                         w1, b1, w2, b2, h_sum, h_max, cnt);
    out_k<<<(NG + 255) / 256, 256, 0, stream>>>(h_sum, h_max, cnt, w3, b3, out);
}

// Round 15
// 203.459 us; speedup vs baseline: 1.1812x; 1.1812x over previous
//
#include <hip/hip_runtime.h>
#include <hip/hip_bf16.h>
#include <hip/hip_fp16.h>

static constexpr int NN = 1000000;   // nodes
static constexpr int NE = 5000000;   // edges
static constexpr int NG = 4096;      // graphs
static constexpr int BIN_SH = 8;                      // 256 nodes per bin
static constexpr int BIN_SZ = 1 << BIN_SH;            // 256
static constexpr int NB = (NN + BIN_SZ - 1) >> BIN_SH;   // 3907 (last bin = 64 nodes, %64==0)
static constexpr int CAP_SH = 11;                     // 2048 edge slots per bin
static constexpr int CAP = 1 << CAP_SH;
static constexpr int EPB = 16384;                     // edges per block for the scatter pass
static constexpr int BIN_BLOCKS = (NE + EPB - 1) / EPB;  // 306 (1024-thread blocks now)
static constexpr int CHUNK = 512;                     // edges per LDS chunk (18 KB -> 8 blocks/CU)

// transform(x) == tanh(x) for finite x. Clamp-free: 1 - 2/(e^{2x}+1) is exact
// at the extremes (e=inf -> 1, e=0 -> -1), no NaN for finite x.
__device__ __forceinline__ float fast_tanh(float x) {
    float e = __expf(2.0f * x);
    return 1.0f - 2.0f * __fdividef(1.0f, e + 1.0f);
}

// ---- Pass 0: pack x into fp16x4 (8 B/node, 8 MB total) for the edge gather ----
__global__ __launch_bounds__(256) void x2h_k(
    const float* __restrict__ x, __half* __restrict__ xh)   // [NN,4]
{
    int i = blockIdx.x * 256 + threadIdx.x;
    if (i >= NN) return;
    union { __half2 h2[2]; uint2 u; } o;
    o.h2[0] = __floats2half2_rn(x[3 * i + 0], x[3 * i + 1]);
    o.h2[1] = __floats2half2_rn(x[3 * i + 2], 0.0f);
    *reinterpret_cast<uint2*>(xh + 4 * (size_t)i) = o.u;
}

// ---- Pass 1: scatter packed (rl, col) into fixed-capacity bins ----
// 1024 threads/block: 16 waves/CU resident (vs 4-5 at 256) to hide the
// random-write + LDS-cursor latency. pack[bin*CAP + k] = (rl << 20) | col.
// binCursor zero-init'd by memset; final binCursor[b] == bin edge count.
__global__ __launch_bounds__(1024) void bin_scatter_k(
    const int* __restrict__ row, const int* __restrict__ col,
    int* __restrict__ binCursor, unsigned int* __restrict__ pack)
{
    __shared__ int hist[NB];          // 15.6 KB
    for (int i = threadIdx.x; i < NB; i += 1024) hist[i] = 0;
    __syncthreads();
    int base = blockIdx.x * EPB;
#pragma unroll 4
    for (int k = 0; k < EPB / 1024; ++k) {
        int e = base + k * 1024 + threadIdx.x;
        if (e < NE) atomicAdd(&hist[row[e] >> BIN_SH], 1);
    }
    __syncthreads();
    // hist[bin] becomes this block's ABSOLUTE write cursor for that bin
    for (int i = threadIdx.x; i < NB; i += 1024) {
        int c = hist[i];
        hist[i] = c ? ((i << CAP_SH) + atomicAdd(&binCursor[i], c)) : 0;
    }
    __syncthreads();
#pragma unroll 4
    for (int k = 0; k < EPB / 1024; ++k) {
        int e = base + k * 1024 + threadIdx.x;
        if (e >= NE) continue;
        int r = row[e];
        int c = col[e];
        int pos = atomicAdd(&hist[r >> BIN_SH], 1);
        pack[pos] = ((unsigned int)(r & (BIN_SZ - 1)) << 20) | (unsigned int)c;
    }
}

// ---- Pass 2: per-bin chunked pipeline (8 blocks/CU for gather latency hiding) ----
// stride-256 pack read -> gather xh[col] (8B, L2/L3) -> edge-parallel MLP1+tanh
// -> fp16 payload counting-sort through LDS (wave-shuffle scan) -> owner pk_add.
__global__ __launch_bounds__(256) void bucket_agg_k(
    const unsigned int* __restrict__ pack,
    const int* __restrict__ binCursor,   // final per-bin counts
    const __half* __restrict__ xh,  // [NN,4]
    const int* __restrict__ batch,
    const float* __restrict__ w1,   // [3,16]
    const float* __restrict__ b1,   // [16]
    const float* __restrict__ w2,   // [16,16]
    const float* __restrict__ b2,   // [16]
    float* __restrict__ h_sum,      // [NG,16]
    unsigned int* __restrict__ h_max, // [NG,16] monotone-encoded
    int* __restrict__ cnt)          // [NG]
{
    __shared__ uint4 pay[CHUNK * 2];   // 16 KB sorted h1-payloads (16 halfs/edge)
    __shared__ int scnt[BIN_SZ];       // hist -> cursor
    __shared__ int sstart[BIN_SZ];     // exclusive starts
    __shared__ int wsum[4];            // per-wave scan sums

    int tid = threadIdx.x;
    int lane = tid & 63, wid = tid >> 6;
    int b = blockIdx.x;
    int nodeBase = b << BIN_SH;
    int nNodes = min(BIN_SZ, NN - nodeBase);   // 256, or 64 for last bin (%64==0)
    int es = b << CAP_SH;
    int ee = es + binCursor[b];

    __half2 acc8[8];
#pragma unroll
    for (int q = 0; q < 8; ++q) acc8[q] = __half2half2(__float2half(0.0f));
    int dg = 0;

    for (int cs = es; cs < ee; cs += CHUNK) {
        int m = min(CHUNK, ee - cs);
        scnt[tid] = 0;
        __syncthreads();                                   // B1

        // stride-256 loads: balanced across threads even in tail chunks
        uint2 gx[2];
        int rl2[2];
#pragma unroll
        for (int k = 0; k < 2; ++k) {
            int e = cs + k * 256 + tid;
            rl2[k] = -1;
            if (e < cs + m) {
                unsigned int p = pack[e];
                int c = (int)(p & 0xFFFFFu);
                rl2[k] = (int)(p >> 20);
                gx[k] = *reinterpret_cast<const uint2*>(xh + 4 * (size_t)c);
                atomicAdd(&scnt[rl2[k]], 1);   // no-return ds_add
            }
        }
        __syncthreads();                                   // B2

        // exclusive scan of scnt via wave shuffles
        int v = scnt[tid];
        int sc = v;
#pragma unroll
        for (int off = 1; off < 64; off <<= 1) {
            int u = __shfl_up(sc, off);
            if (lane >= off) sc += u;
        }
        if (lane == 63) wsum[wid] = sc;
        __syncthreads();                                   // B3
        int pre = 0;
#pragma unroll
        for (int w = 0; w < 4; ++w) pre += (w < wid) ? wsum[w] : 0;
        int ex = pre + sc - v;
        sstart[tid] = ex;
        scnt[tid] = ex;
        __syncthreads();                                   // B4

        // EDGE-PARALLEL MLP1 + tanh (balanced), then counting-sort scatter
#pragma unroll
        for (int k = 0; k < 2; ++k) {
            if (rl2[k] >= 0) {
                union { uint2 u; __half2 h2[2]; } xi;
                xi.u = gx[k];
                float2 x01 = __half22float2(xi.h2[0]);
                float x2v = __low2float(xi.h2[1]);
                union { __half2 h2[8]; uint4 u[2]; } o;
#pragma unroll
                for (int q = 0; q < 8; ++q) {
                    float va = fmaf(x2v, w1[32 + 2 * q], fmaf(x01.y, w1[16 + 2 * q],
                               fmaf(x01.x, w1[2 * q], b1[2 * q])));
                    float vb = fmaf(x2v, w1[33 + 2 * q], fmaf(x01.y, w1[17 + 2 * q],
                               fmaf(x01.x, w1[2 * q + 1], b1[2 * q + 1])));
                    o.h2[q] = __floats2half2_rn(fast_tanh(va), fast_tanh(vb));
                }
                int pos = atomicAdd(&scnt[rl2[k]], 1);   // returning ds_add_rtn
                pay[2 * pos + 0] = o.u[0];
                pay[2 * pos + 1] = o.u[1];
            }
        }
        __syncthreads();                                   // B5

        // owner accumulation: thread tid owns node tid; 8 pk_add_f16 per edge
        if (tid < nNodes) {
            int s0 = sstart[tid];
            int e0 = (tid < 255) ? sstart[tid + 1] : m;
            dg += e0 - s0;
            for (int e = s0; e < e0; ++e) {
                union { uint4 u; __half2 h2[4]; } ua, ub;
                ua.u = pay[2 * e + 0];
                ub.u = pay[2 * e + 1];
#pragma unroll
                for (int q = 0; q < 4; ++q) {
                    acc8[q] = __hadd2(acc8[q], ua.h2[q]);
                    acc8[4 + q] = __hadd2(acc8[4 + q], ub.h2[q]);
                }
            }
        }
        __syncthreads();                                   // B6
    }

    // node phase: normalize, MLP2, tanh, segmented wave reduction over sorted batch
    if (tid < nNodes) {                       // wave-uniform (nNodes % 64 == 0)
        float acc[16];
#pragma unroll
        for (int q = 0; q < 8; ++q) {
            float2 f = __half22float2(acc8[q]);
            acc[2 * q + 0] = f.x;
            acc[2 * q + 1] = f.y;
        }
        float inv = 1.0f / fmaxf((float)dg, 1.0f);
        float s[16];
#pragma unroll
        for (int j = 0; j < 16; ++j) s[j] = b2[j];
#pragma unroll
        for (int k = 0; k < 16; ++k) {
            float a = acc[k] * inv;
#pragma unroll
            for (int j = 0; j < 16; ++j) s[j] = fmaf(a, w2[16 * k + j], s[j]);
        }
        float m[16];
#pragma unroll
        for (int j = 0; j < 16; ++j) { s[j] = fast_tanh(s[j]); m[j] = s[j]; }

        int g = batch[nodeBase + tid];
        int gp = __shfl_up(g, 1);
        int head = (lane == 0) || (g != gp);
        unsigned long long hm = __ballot(head != 0);

        int f = head;
#pragma unroll
        for (int off = 1; off < 64; off <<= 1) {
            int fu = __shfl_up(f, off);
            bool take = (lane >= off) && (f == 0);
#pragma unroll
            for (int j = 0; j < 16; ++j) {
                float su = __shfl_up(s[j], off);
                float mu = __shfl_up(m[j], off);
                if (take) { s[j] += su; m[j] = fmaxf(m[j], mu); }
            }
            if (lane >= off) f |= fu;
        }

        int hnext = __shfl_down(head, 1);
        bool is_last = (lane == 63) || (hnext != 0);
        if (is_last) {
            unsigned long long below = hm & (~0ULL >> (63 - lane));
            int start = 63 - __clzll(below);
            int seglen = lane - start + 1;
#pragma unroll
            for (int j = 0; j < 16; ++j) {
                unsafeAtomicAdd(&h_sum[16 * g + j], s[j]);
                atomicMax(&h_max[16 * g + j], __float_as_uint(m[j] + 2.0f));
            }
            atomicAdd(&cnt[g], seglen);
        }
    }
}

// ---- Pass 3: head ----
__global__ __launch_bounds__(256) void out_k(
    const float* __restrict__ h_sum,
    const unsigned int* __restrict__ h_max,
    const int* __restrict__ cnt,
    const float* __restrict__ w3,   // [32]
    const float* __restrict__ b3,   // [1]
    float* __restrict__ out)        // [NG]
{
    int g = blockIdx.x * 256 + threadIdx.x;
    if (g >= NG) return;
    float invc = 1.0f / fmaxf((float)cnt[g], 1.0f);
    float acc = b3[0];
#pragma unroll
    for (int j = 0; j < 16; ++j) {
        float mean = h_sum[16 * g + j] * invc;
        unsigned int e = h_max[16 * g + j];
        float mx = (e == 0u) ? 0.0f : (__uint_as_float(e) - 2.0f);
        acc = fmaf(mean, w3[j], fmaf(mx, w3[16 + j], acc));
    }
    out[g] = 1.0f / (1.0f + __expf(-acc));
}

extern "C" void kernel_launch(void* const* d_in, const int* in_sizes, int n_in,
                              void* d_out, int out_size, void* d_ws, size_t ws_size,
                              hipStream_t stream)
{
    const float* x   = (const float*)d_in[0];
    const int*   ei  = (const int*)d_in[1];   // row = ei, col = ei + NE
    const int*   bat = (const int*)d_in[2];
    const float* w1  = (const float*)d_in[3];
    const float* b1  = (const float*)d_in[4];
    const float* w2  = (const float*)d_in[5];
    const float* b2  = (const float*)d_in[6];
    const float* w3  = (const float*)d_in[7];
    const float* b3  = (const float*)d_in[8];
    float* out = (float*)d_out;

    char* ws = (char*)d_ws;
    size_t off = 0;
    // --- zeroed region (one small memset, ~0.57 MB) ---
    int* binCursor = (int*)(ws + off);         off += 16384;                 // NB ints, padded
    float* h_sum  = (float*)(ws + off);        off += (size_t)NG * 16 * 4;
    unsigned int* h_max = (unsigned int*)(ws + off); off += (size_t)NG * 16 * 4;
    int* cnt      = (int*)(ws + off);          off += (size_t)NG * 4;
    size_t zero_bytes = off;
    // --- non-zeroed scratch (total ~41 MB) ---
    unsigned int* pack = (unsigned int*)(ws + off); off += (size_t)NB * CAP * 4; // 32 MB
    __half* xh    = (__half*)(ws + off);       off += (size_t)NN * 4 * 2;    // 8 MB

    hipMemsetAsync(d_ws, 0, zero_bytes, stream);

    x2h_k<<<(NN + 255) / 256, 256, 0, stream>>>(x, xh);
    bin_scatter_k<<<BIN_BLOCKS, 1024, 0, stream>>>(ei, ei + NE, binCursor, pack);
    bucket_agg_k<<<NB, 256, 0, stream>>>(pack, binCursor, xh, bat,
                                         w1, b1, w2, b2, h_sum, h_max, cnt);
    out_k<<<(NG + 255) / 256, 256, 0, stream>>>(h_sum, h_max, cnt, w3, b3, out);
}

// Round 16
// 191.746 us; speedup vs baseline: 1.2534x; 1.0611x over previous
//
#include <hip/hip_runtime.h>
#include <hip/hip_bf16.h>
#include <hip/hip_fp16.h>

static constexpr int NN = 1000000;   // nodes
static constexpr int NE = 5000000;   // edges
static constexpr int NG = 4096;      // graphs
static constexpr int BIN_SH = 8;                      // 256 nodes per bin
static constexpr int BIN_SZ = 1 << BIN_SH;            // 256
static constexpr int NB = (NN + BIN_SZ - 1) >> BIN_SH;   // 3907 (last bin = 64 nodes, %64==0)
static constexpr int CAP_SH = 11;                     // 2048 edge slots per bin
static constexpr int CAP = 1 << CAP_SH;
static constexpr int EPB = 16384;                     // edges per block for the scatter pass
static constexpr int EPW = EPB / 1024;                // 16 edges per thread in scatter
static constexpr int BIN_BLOCKS = (NE + EPB - 1) / EPB;  // 306 (1024-thread blocks)
static constexpr int CHUNK = 512;                     // edges per LDS chunk (18 KB -> 8 blocks/CU)

// transform(x) == tanh(x) for finite x. Clamp-free: 1 - 2/(e^{2x}+1) is exact
// at the extremes (e=inf -> 1, e=0 -> -1), no NaN for finite x.
__device__ __forceinline__ float fast_tanh(float x) {
    float e = __expf(2.0f * x);
    return 1.0f - 2.0f * __fdividef(1.0f, e + 1.0f);
}

// ---- Pass 0: pack x into fp16x4 (8 B/node, 8 MB total) for the edge gather ----
__global__ __launch_bounds__(256) void x2h_k(
    const float* __restrict__ x, __half* __restrict__ xh)   // [NN,4]
{
    int i = blockIdx.x * 256 + threadIdx.x;
    if (i >= NN) return;
    union { __half2 h2[2]; uint2 u; } o;
    o.h2[0] = __floats2half2_rn(x[3 * i + 0], x[3 * i + 1]);
    o.h2[1] = __floats2half2_rn(x[3 * i + 2], 0.0f);
    *reinterpret_cast<uint2*>(xh + 4 * (size_t)i) = o.u;
}

// ---- Pass 1: scatter packed (rl, col) into fixed-capacity bins ----
// Edges loaded ONCE into registers (no row re-read); all 16 returning LDS
// atomics issued back-to-back for max outstanding ops, then all 16 writes.
// pack[bin*CAP + k] = (rl << 20) | col. binCursor zero-init'd by memset.
__global__ __launch_bounds__(1024) void bin_scatter_k(
    const int* __restrict__ row, const int* __restrict__ col,
    int* __restrict__ binCursor, unsigned int* __restrict__ pack)
{
    __shared__ int hist[NB];          // 15.6 KB -> 2 blocks/CU
    for (int i = threadIdx.x; i < NB; i += 1024) hist[i] = 0;
    __syncthreads();
    int base = blockIdx.x * EPB;

    int r[EPW], c[EPW];
    bool val[EPW];
#pragma unroll
    for (int k = 0; k < EPW; ++k) {
        int e = base + k * 1024 + threadIdx.x;
        val[k] = e < NE;
        r[k] = val[k] ? row[e] : 0;
        c[k] = val[k] ? col[e] : 0;
    }
#pragma unroll
    for (int k = 0; k < EPW; ++k)
        if (val[k]) atomicAdd(&hist[r[k] >> BIN_SH], 1);
    __syncthreads();
    // hist[bin] becomes this block's ABSOLUTE write cursor for that bin
    for (int i = threadIdx.x; i < NB; i += 1024) {
        int cc = hist[i];
        hist[i] = cc ? ((i << CAP_SH) + atomicAdd(&binCursor[i], cc)) : 0;
    }
    __syncthreads();
    int pos[EPW];
#pragma unroll
    for (int k = 0; k < EPW; ++k)
        if (val[k]) pos[k] = atomicAdd(&hist[r[k] >> BIN_SH], 1);   // 16 outstanding
#pragma unroll
    for (int k = 0; k < EPW; ++k)
        if (val[k]) pack[pos[k]] = ((unsigned int)(r[k] & (BIN_SZ - 1)) << 20)
                                   | (unsigned int)c[k];
}

// ---- Pass 2: per-bin chunked pipeline, software-pipelined across chunks ----
// Chunk i+1's pack-read + xh-gather issue during chunk i's sort/owner phases,
// hiding the random-gather latency under compute instead of stalling on it.
__global__ __launch_bounds__(256) void bucket_agg_k(
    const unsigned int* __restrict__ pack,
    const int* __restrict__ binCursor,   // final per-bin counts
    const __half* __restrict__ xh,  // [NN,4]
    const int* __restrict__ batch,
    const float* __restrict__ w1,   // [3,16]
    const float* __restrict__ b1,   // [16]
    const float* __restrict__ w2,   // [16,16]
    const float* __restrict__ b2,   // [16]
    float* __restrict__ h_sum,      // [NG,16]
    unsigned int* __restrict__ h_max, // [NG,16] monotone-encoded
    int* __restrict__ cnt)          // [NG]
{
    __shared__ uint4 pay[CHUNK * 2];   // 16 KB sorted h1-payloads (16 halfs/edge)
    __shared__ int scnt[BIN_SZ];       // hist -> cursor
    __shared__ int sstart[BIN_SZ];     // exclusive starts
    __shared__ int wsum[4];            // per-wave scan sums

    int tid = threadIdx.x;
    int lane = tid & 63, wid = tid >> 6;
    int b = blockIdx.x;
    int nodeBase = b << BIN_SH;
    int nNodes = min(BIN_SZ, NN - nodeBase);   // 256, or 64 for last bin (%64==0)
    int es = b << CAP_SH;
    int ee = es + binCursor[b];

    __half2 acc8[8];
#pragma unroll
    for (int q = 0; q < 8; ++q) acc8[q] = __half2half2(__float2half(0.0f));
    int dg = 0;

    // prefetch chunk 0
    uint2 gxA[2]; int rlA[2];
    rlA[0] = rlA[1] = -1;
    if (es < ee) {
        int mm = min(CHUNK, ee - es);
#pragma unroll
        for (int k = 0; k < 2; ++k) {
            int off = k * 256 + tid;
            if (off < mm) {
                unsigned int p = pack[es + off];
                rlA[k] = (int)(p >> 20);
                gxA[k] = *reinterpret_cast<const uint2*>(xh + 4 * (size_t)(p & 0xFFFFFu));
            }
        }
    }

    for (int cs = es; cs < ee; cs += CHUNK) {
        int m = min(CHUNK, ee - cs);
        scnt[tid] = 0;
        __syncthreads();                                   // B1

        // histogram current chunk from prefetched rl
#pragma unroll
        for (int k = 0; k < 2; ++k)
            if (rlA[k] >= 0) atomicAdd(&scnt[rlA[k]], 1);  // no-return ds_add
        __syncthreads();                                   // B2

        // exclusive scan of scnt via wave shuffles
        int v = scnt[tid];
        int sc = v;
#pragma unroll
        for (int off = 1; off < 64; off <<= 1) {
            int u = __shfl_up(sc, off);
            if (lane >= off) sc += u;
        }
        if (lane == 63) wsum[wid] = sc;
        __syncthreads();                                   // B3
        int pre = 0;
#pragma unroll
        for (int w = 0; w < 4; ++w) pre += (w < wid) ? wsum[w] : 0;
        int ex = pre + sc - v;
        sstart[tid] = ex;
        scnt[tid] = ex;
        __syncthreads();                                   // B4

        // EDGE-PARALLEL MLP1 + tanh (balanced), then counting-sort scatter
#pragma unroll
        for (int k = 0; k < 2; ++k) {
            if (rlA[k] >= 0) {
                union { uint2 u; __half2 h2[2]; } xi;
                xi.u = gxA[k];
                float2 x01 = __half22float2(xi.h2[0]);
                float x2v = __low2float(xi.h2[1]);
                union { __half2 h2[8]; uint4 u[2]; } o;
#pragma unroll
                for (int q = 0; q < 8; ++q) {
                    float va = fmaf(x2v, w1[32 + 2 * q], fmaf(x01.y, w1[16 + 2 * q],
                               fmaf(x01.x, w1[2 * q], b1[2 * q])));
                    float vb = fmaf(x2v, w1[33 + 2 * q], fmaf(x01.y, w1[17 + 2 * q],
                               fmaf(x01.x, w1[2 * q + 1], b1[2 * q + 1])));
                    o.h2[q] = __floats2half2_rn(fast_tanh(va), fast_tanh(vb));
                }
                int pos = atomicAdd(&scnt[rlA[k]], 1);   // returning ds_add_rtn
                pay[2 * pos + 0] = o.u[0];
                pay[2 * pos + 1] = o.u[1];
            }
        }

        // prefetch next chunk: global loads overlap owner phase below
        uint2 gxB[2]; int rlB[2];
        rlB[0] = rlB[1] = -1;
        if (cs + CHUNK < ee) {
            int mm = min(CHUNK, ee - (cs + CHUNK));
#pragma unroll
            for (int k = 0; k < 2; ++k) {
                int off = k * 256 + tid;
                if (off < mm) {
                    unsigned int p = pack[cs + CHUNK + off];
                    rlB[k] = (int)(p >> 20);
                    gxB[k] = *reinterpret_cast<const uint2*>(xh + 4 * (size_t)(p & 0xFFFFFu));
                }
            }
        }
        __syncthreads();                                   // B5

        // owner accumulation: thread tid owns node tid; 8 pk_add_f16 per edge
        if (tid < nNodes) {
            int s0 = sstart[tid];
            int e0 = (tid < 255) ? sstart[tid + 1] : m;
            dg += e0 - s0;
            for (int e = s0; e < e0; ++e) {
                union { uint4 u; __half2 h2[4]; } ua, ub;
                ua.u = pay[2 * e + 0];
                ub.u = pay[2 * e + 1];
#pragma unroll
                for (int q = 0; q < 4; ++q) {
                    acc8[q] = __hadd2(acc8[q], ua.h2[q]);
                    acc8[4 + q] = __hadd2(acc8[4 + q], ub.h2[q]);
                }
            }
        }
        __syncthreads();                                   // B6

#pragma unroll
        for (int k = 0; k < 2; ++k) { gxA[k] = gxB[k]; rlA[k] = rlB[k]; }
    }

    // node phase: normalize, MLP2, tanh, segmented wave reduction over sorted batch
    if (tid < nNodes) {                       // wave-uniform (nNodes % 64 == 0)
        float acc[16];
#pragma unroll
        for (int q = 0; q < 8; ++q) {
            float2 f = __half22float2(acc8[q]);
            acc[2 * q + 0] = f.x;
            acc[2 * q + 1] = f.y;
        }
        float inv = 1.0f / fmaxf((float)dg, 1.0f);
        float s[16];
#pragma unroll
        for (int j = 0; j < 16; ++j) s[j] = b2[j];
#pragma unroll
        for (int k = 0; k < 16; ++k) {
            float a = acc[k] * inv;
#pragma unroll
            for (int j = 0; j < 16; ++j) s[j] = fmaf(a, w2[16 * k + j], s[j]);
        }
        float m[16];
#pragma unroll
        for (int j = 0; j < 16; ++j) { s[j] = fast_tanh(s[j]); m[j] = s[j]; }

        int g = batch[nodeBase + tid];
        int gp = __shfl_up(g, 1);
        int head = (lane == 0) || (g != gp);
        unsigned long long hm = __ballot(head != 0);

        int f = head;
#pragma unroll
        for (int off = 1; off < 64; off <<= 1) {
            int fu = __shfl_up(f, off);
            bool take = (lane >= off) && (f == 0);
#pragma unroll
            for (int j = 0; j < 16; ++j) {
                float su = __shfl_up(s[j], off);
                float mu = __shfl_up(m[j], off);
                if (take) { s[j] += su; m[j] = fmaxf(m[j], mu); }
            }
            if (lane >= off) f |= fu;
        }

        int hnext = __shfl_down(head, 1);
        bool is_last = (lane == 63) || (hnext != 0);
        if (is_last) {
            unsigned long long below = hm & (~0ULL >> (63 - lane));
            int start = 63 - __clzll(below);
            int seglen = lane - start + 1;
#pragma unroll
            for (int j = 0; j < 16; ++j) {
                unsafeAtomicAdd(&h_sum[16 * g + j], s[j]);
                atomicMax(&h_max[16 * g + j], __float_as_uint(m[j] + 2.0f));
            }
            atomicAdd(&cnt[g], seglen);
        }
    }
}

// ---- Pass 3: head ----
__global__ __launch_bounds__(256) void out_k(
    const float* __restrict__ h_sum,
    const unsigned int* __restrict__ h_max,
    const int* __restrict__ cnt,
    const float* __restrict__ w3,   // [32]
    const float* __restrict__ b3,   // [1]
    float* __restrict__ out)        // [NG]
{
    int g = blockIdx.x * 256 + threadIdx.x;
    if (g >= NG) return;
    float invc = 1.0f / fmaxf((float)cnt[g], 1.0f);
    float acc = b3[0];
#pragma unroll
    for (int j = 0; j < 16; ++j) {
        float mean = h_sum[16 * g + j] * invc;
        unsigned int e = h_max[16 * g + j];
        float mx = (e == 0u) ? 0.0f : (__uint_as_float(e) - 2.0f);
        acc = fmaf(mean, w3[j], fmaf(mx, w3[16 + j], acc));
    }
    out[g] = 1.0f / (1.0f + __expf(-acc));
}

extern "C" void kernel_launch(void* const* d_in, const int* in_sizes, int n_in,
                              void* d_out, int out_size, void* d_ws, size_t ws_size,
                              hipStream_t stream)
{
    const float* x   = (const float*)d_in[0];
    const int*   ei  = (const int*)d_in[1];   // row = ei, col = ei + NE
    const int*   bat = (const int*)d_in[2];
    const float* w1  = (const float*)d_in[3];
    const float* b1  = (const float*)d_in[4];
    const float* w2  = (const float*)d_in[5];
    const float* b2  = (const float*)d_in[6];
    const float* w3  = (const float*)d_in[7];
    const float* b3  = (const float*)d_in[8];
    float* out = (float*)d_out;

    char* ws = (char*)d_ws;
    size_t off = 0;
    // --- zeroed region (one small memset, ~0.57 MB) ---
    int* binCursor = (int*)(ws + off);         off += 16384;                 // NB ints, padded
    float* h_sum  = (float*)(ws + off);        off += (size_t)NG * 16 * 4;
    unsigned int* h_max = (unsigned int*)(ws + off); off += (size_t)NG * 16 * 4;
    int* cnt      = (int*)(ws + off);          off += (size_t)NG * 4;
    size_t zero_bytes = off;
    // --- non-zeroed scratch (total ~41 MB) ---
    unsigned int* pack = (unsigned int*)(ws + off); off += (size_t)NB * CAP * 4; // 32 MB
    __half* xh    = (__half*)(ws + off);       off += (size_t)NN * 4 * 2;    // 8 MB

    hipMemsetAsync(d_ws, 0, zero_bytes, stream);

    x2h_k<<<(NN + 255) / 256, 256, 0, stream>>>(x, xh);
    bin_scatter_k<<<BIN_BLOCKS, 1024, 0, stream>>>(ei, ei + NE, binCursor, pack);
    bucket_agg_k<<<NB, 256, 0, stream>>>(pack, binCursor, xh, bat,
                                         w1, b1, w2, b2, h_sum, h_max, cnt);
    out_k<<<(NG + 255) / 256, 256, 0, stream>>>(h_sum, h_max, cnt, w3, b3, out);
}

// Round 17
// 184.283 us; speedup vs baseline: 1.3042x; 1.0405x over previous
//
#include <hip/hip_runtime.h>
#include <hip/hip_bf16.h>
#include <hip/hip_fp16.h>

static constexpr int NN = 1000000;   // nodes
static constexpr int NE = 5000000;   // edges
static constexpr int NG = 4096;      // graphs
static constexpr int BIN_SH = 8;                      // 256 nodes per bin
static constexpr int BIN_SZ = 1 << BIN_SH;            // 256
static constexpr int NB = (NN + BIN_SZ - 1) >> BIN_SH;   // 3907 (last bin = 64 nodes, %64==0)
static constexpr int CAP_SH = 11;                     // 2048 edge slots per bin
static constexpr int CAP = 1 << CAP_SH;
static constexpr int EPB = 16384;                     // edges per block for the scatter pass
static constexpr int EPW = EPB / 1024;                // 16 edges per thread in scatter
static constexpr int BIN_BLOCKS = (NE + EPB - 1) / EPB;  // 306 (1024-thread blocks)
static constexpr int CHUNK = 512;                     // edges per LDS chunk (18 KB -> 8 blocks/CU)
static constexpr float KEXP = 2.8853900817779268f;    // 2*log2(e): tanh(v)=1-2/(2^(K v)+1)

__device__ __forceinline__ float exp2_fast(float x) {
#if __has_builtin(__builtin_amdgcn_exp2f)
    return __builtin_amdgcn_exp2f(x);
#else
    return exp2f(x);
#endif
}

// tanh from pre-scaled argument s = KEXP * v: tanh(v) = 1 - 2/(2^s + 1).
// Exact at extremes (2^s=inf -> 1, 2^s=0 -> -1); no clamp needed.
__device__ __forceinline__ float tanh_scaled(float s) {
    float e = exp2_fast(s);
    return fmaf(-2.0f, __frcp_rn(e + 1.0f), 1.0f);
}

// full-precision tanh for the node-phase (argument not pre-scaled)
__device__ __forceinline__ float fast_tanh(float x) {
    float e = __expf(2.0f * x);
    return 1.0f - 2.0f * __fdividef(1.0f, e + 1.0f);
}

// ---- Pass 1: x->fp16 pack (grid-stride prologue) + scatter (rl,col) into bins ----
// x2h folded in: its streaming work rides the scatter's idle issue slots.
// pack[bin*CAP + k] = (rl << 20) | col. binCursor zero-init'd by memset.
__global__ __launch_bounds__(1024) void bin_scatter_k(
    const int* __restrict__ row, const int* __restrict__ col,
    const float* __restrict__ x,
    int* __restrict__ binCursor, unsigned int* __restrict__ pack,
    __half* __restrict__ xh)
{
    __shared__ int hist[NB];          // 15.6 KB -> 2 blocks/CU
    // x -> fp16x4 pack (independent of the edge phase; consumed by bucket_agg)
    for (int i = blockIdx.x * 1024 + threadIdx.x; i < NN; i += BIN_BLOCKS * 1024) {
        union { __half2 h2[2]; uint2 u; } o;
        o.h2[0] = __floats2half2_rn(x[3 * i + 0], x[3 * i + 1]);
        o.h2[1] = __floats2half2_rn(x[3 * i + 2], 0.0f);
        *reinterpret_cast<uint2*>(xh + 4 * (size_t)i) = o.u;
    }

    for (int i = threadIdx.x; i < NB; i += 1024) hist[i] = 0;
    __syncthreads();
    int base = blockIdx.x * EPB;

    int r[EPW], c[EPW];
    bool val[EPW];
#pragma unroll
    for (int k = 0; k < EPW; ++k) {
        int e = base + k * 1024 + threadIdx.x;
        val[k] = e < NE;
        r[k] = val[k] ? row[e] : 0;
        c[k] = val[k] ? col[e] : 0;
    }
#pragma unroll
    for (int k = 0; k < EPW; ++k)
        if (val[k]) atomicAdd(&hist[r[k] >> BIN_SH], 1);
    __syncthreads();
    // hist[bin] becomes this block's ABSOLUTE write cursor for that bin
    for (int i = threadIdx.x; i < NB; i += 1024) {
        int cc = hist[i];
        hist[i] = cc ? ((i << CAP_SH) + atomicAdd(&binCursor[i], cc)) : 0;
    }
    __syncthreads();
    int pos[EPW];
#pragma unroll
    for (int k = 0; k < EPW; ++k)
        if (val[k]) pos[k] = atomicAdd(&hist[r[k] >> BIN_SH], 1);   // 16 outstanding
#pragma unroll
    for (int k = 0; k < EPW; ++k)
        if (val[k]) pack[pos[k]] = ((unsigned int)(r[k] & (BIN_SZ - 1)) << 20)
                                   | (unsigned int)c[k];
}

// ---- Pass 2: per-bin chunked pipeline, software-pipelined across chunks ----
// Prefetch of chunk i+1 issues BEFORE chunk i's scan/MLP/sort/owner phases,
// spanning maximum compute. MLP1 args pre-scaled by KEXP so tanh needs no muls.
__global__ __launch_bounds__(256) void bucket_agg_k(
    const unsigned int* __restrict__ pack,
    const int* __restrict__ binCursor,   // final per-bin counts
    const __half* __restrict__ xh,  // [NN,4]
    const int* __restrict__ batch,
    const float* __restrict__ w1,   // [3,16]
    const float* __restrict__ b1,   // [16]
    const float* __restrict__ w2,   // [16,16]
    const float* __restrict__ b2,   // [16]
    float* __restrict__ h_sum,      // [NG,16]
    unsigned int* __restrict__ h_max, // [NG,16] monotone-encoded
    int* __restrict__ cnt)          // [NG]
{
    __shared__ uint4 pay[CHUNK * 2];   // 16 KB sorted h1-payloads (16 halfs/edge)
    __shared__ int scnt[BIN_SZ];       // hist -> cursor
    __shared__ int sstart[BIN_SZ];     // exclusive starts
    __shared__ int wsum[4];            // per-wave scan sums

    int tid = threadIdx.x;
    int lane = tid & 63, wid = tid >> 6;
    int b = blockIdx.x;
    int nodeBase = b << BIN_SH;
    int nNodes = min(BIN_SZ, NN - nodeBase);   // 256, or 64 for last bin (%64==0)
    int es = b << CAP_SH;
    int ee = es + binCursor[b];

    // one-time: bias pre-scaled by KEXP (16 VGPR)
    float b1s[16];
#pragma unroll
    for (int j = 0; j < 16; ++j) b1s[j] = b1[j] * KEXP;

    __half2 acc8[8];
#pragma unroll
    for (int q = 0; q < 8; ++q) acc8[q] = __half2half2(__float2half(0.0f));
    int dg = 0;

    // prefetch chunk 0
    uint2 gxA[2]; int rlA[2];
    rlA[0] = rlA[1] = -1;
    if (es < ee) {
        int mm = min(CHUNK, ee - es);
#pragma unroll
        for (int k = 0; k < 2; ++k) {
            int off = k * 256 + tid;
            if (off < mm) {
                unsigned int p = pack[es + off];
                rlA[k] = (int)(p >> 20);
                gxA[k] = *reinterpret_cast<const uint2*>(xh + 4 * (size_t)(p & 0xFFFFFu));
            }
        }
    }

    for (int cs = es; cs < ee; cs += CHUNK) {
        int m = min(CHUNK, ee - cs);
        scnt[tid] = 0;
        __syncthreads();                                   // B1

        // histogram current chunk from prefetched rl
#pragma unroll
        for (int k = 0; k < 2; ++k)
            if (rlA[k] >= 0) atomicAdd(&scnt[rlA[k]], 1);  // no-return ds_add

        // prefetch next chunk NOW: loads span scan+MLP+sort+owner phases
        uint2 gxB[2]; int rlB[2];
        rlB[0] = rlB[1] = -1;
        if (cs + CHUNK < ee) {
            int mm = min(CHUNK, ee - (cs + CHUNK));
#pragma unroll
            for (int k = 0; k < 2; ++k) {
                int off = k * 256 + tid;
                if (off < mm) {
                    unsigned int p = pack[cs + CHUNK + off];
                    rlB[k] = (int)(p >> 20);
                    gxB[k] = *reinterpret_cast<const uint2*>(xh + 4 * (size_t)(p & 0xFFFFFu));
                }
            }
        }
        __syncthreads();                                   // B2

        // exclusive scan of scnt via wave shuffles
        int v = scnt[tid];
        int sc = v;
#pragma unroll
        for (int off = 1; off < 64; off <<= 1) {
            int u = __shfl_up(sc, off);
            if (lane >= off) sc += u;
        }
        if (lane == 63) wsum[wid] = sc;
        __syncthreads();                                   // B3
        int pre = 0;
#pragma unroll
        for (int w = 0; w < 4; ++w) pre += (w < wid) ? wsum[w] : 0;
        int ex = pre + sc - v;
        sstart[tid] = ex;
        scnt[tid] = ex;
        __syncthreads();                                   // B4

        // EDGE-PARALLEL MLP1 + tanh (pre-scaled args), then counting-sort scatter
#pragma unroll
        for (int k = 0; k < 2; ++k) {
            if (rlA[k] >= 0) {
                union { uint2 u; __half2 h2[2]; } xi;
                xi.u = gxA[k];
                float2 x01 = __half22float2(xi.h2[0]);
                float xs0 = x01.x * KEXP;
                float xs1 = x01.y * KEXP;
                float xs2 = __low2float(xi.h2[1]) * KEXP;
                union { __half2 h2[8]; uint4 u[2]; } o;
#pragma unroll
                for (int q = 0; q < 8; ++q) {
                    float va = fmaf(xs2, w1[32 + 2 * q], fmaf(xs1, w1[16 + 2 * q],
                               fmaf(xs0, w1[2 * q], b1s[2 * q])));
                    float vb = fmaf(xs2, w1[33 + 2 * q], fmaf(xs1, w1[17 + 2 * q],
                               fmaf(xs0, w1[2 * q + 1], b1s[2 * q + 1])));
                    o.h2[q] = __floats2half2_rn(tanh_scaled(va), tanh_scaled(vb));
                }
                int pos = atomicAdd(&scnt[rlA[k]], 1);   // returning ds_add_rtn
                pay[2 * pos + 0] = o.u[0];
                pay[2 * pos + 1] = o.u[1];
            }
        }
        __syncthreads();                                   // B5

        // owner accumulation: thread tid owns node tid; 8 pk_add_f16 per edge
        if (tid < nNodes) {
            int s0 = sstart[tid];
            int e0 = (tid < 255) ? sstart[tid + 1] : m;
            dg += e0 - s0;
            for (int e = s0; e < e0; ++e) {
                union { uint4 u; __half2 h2[4]; } ua, ub;
                ua.u = pay[2 * e + 0];
                ub.u = pay[2 * e + 1];
#pragma unroll
                for (int q = 0; q < 4; ++q) {
                    acc8[q] = __hadd2(acc8[q], ua.h2[q]);
                    acc8[4 + q] = __hadd2(acc8[4 + q], ub.h2[q]);
                }
            }
        }
        __syncthreads();                                   // B6

#pragma unroll
        for (int k = 0; k < 2; ++k) { gxA[k] = gxB[k]; rlA[k] = rlB[k]; }
    }

    // node phase: normalize, MLP2, tanh, segmented wave reduction over sorted batch
    if (tid < nNodes) {                       // wave-uniform (nNodes % 64 == 0)
        float acc[16];
#pragma unroll
        for (int q = 0; q < 8; ++q) {
            float2 f = __half22float2(acc8[q]);
            acc[2 * q + 0] = f.x;
            acc[2 * q + 1] = f.y;
        }
        float inv = 1.0f / fmaxf((float)dg, 1.0f);
        float s[16];
#pragma unroll
        for (int j = 0; j < 16; ++j) s[j] = b2[j];
#pragma unroll
        for (int k = 0; k < 16; ++k) {
            float a = acc[k] * inv;
#pragma unroll
            for (int j = 0; j < 16; ++j) s[j] = fmaf(a, w2[16 * k + j], s[j]);
        }
        float m[16];
#pragma unroll
        for (int j = 0; j < 16; ++j) { s[j] = fast_tanh(s[j]); m[j] = s[j]; }

        int g = batch[nodeBase + tid];
        int gp = __shfl_up(g, 1);
        int head = (lane == 0) || (g != gp);
        unsigned long long hm = __ballot(head != 0);

        int f = head;
#pragma unroll
        for (int off = 1; off < 64; off <<= 1) {
            int fu = __shfl_up(f, off);
            bool take = (lane >= off) && (f == 0);
#pragma unroll
            for (int j = 0; j < 16; ++j) {
                float su = __shfl_up(s[j], off);
                float mu = __shfl_up(m[j], off);
                if (take) { s[j] += su; m[j] = fmaxf(m[j], mu); }
            }
            if (lane >= off) f |= fu;
        }

        int hnext = __shfl_down(head, 1);
        bool is_last = (lane == 63) || (hnext != 0);
        if (is_last) {
            unsigned long long below = hm & (~0ULL >> (63 - lane));
            int start = 63 - __clzll(below);
            int seglen = lane - start + 1;
#pragma unroll
            for (int j = 0; j < 16; ++j) {
                unsafeAtomicAdd(&h_sum[16 * g + j], s[j]);
                atomicMax(&h_max[16 * g + j], __float_as_uint(m[j] + 2.0f));
            }
            atomicAdd(&cnt[g], seglen);
        }
    }
}

// ---- Pass 3: head ----
__global__ __launch_bounds__(256) void out_k(
    const float* __restrict__ h_sum,
    const unsigned int* __restrict__ h_max,
    const int* __restrict__ cnt,
    const float* __restrict__ w3,   // [32]
    const float* __restrict__ b3,   // [1]
    float* __restrict__ out)        // [NG]
{
    int g = blockIdx.x * 256 + threadIdx.x;
    if (g >= NG) return;
    float invc = 1.0f / fmaxf((float)cnt[g], 1.0f);
    float acc = b3[0];
#pragma unroll
    for (int j = 0; j < 16; ++j) {
        float mean = h_sum[16 * g + j] * invc;
        unsigned int e = h_max[16 * g + j];
        float mx = (e == 0u) ? 0.0f : (__uint_as_float(e) - 2.0f);
        acc = fmaf(mean, w3[j], fmaf(mx, w3[16 + j], acc));
    }
    out[g] = 1.0f / (1.0f + __expf(-acc));
}

extern "C" void kernel_launch(void* const* d_in, const int* in_sizes, int n_in,
                              void* d_out, int out_size, void* d_ws, size_t ws_size,
                              hipStream_t stream)
{
    const float* x   = (const float*)d_in[0];
    const int*   ei  = (const int*)d_in[1];   // row = ei, col = ei + NE
    const int*   bat = (const int*)d_in[2];
    const float* w1  = (const float*)d_in[3];
    const float* b1  = (const float*)d_in[4];
    const float* w2  = (const float*)d_in[5];
    const float* b2  = (const float*)d_in[6];
    const float* w3  = (const float*)d_in[7];
    const float* b3  = (const float*)d_in[8];
    float* out = (float*)d_out;

    char* ws = (char*)d_ws;
    size_t off = 0;
    // --- zeroed region (one small memset, ~0.57 MB) ---
    int* binCursor = (int*)(ws + off);         off += 16384;                 // NB ints, padded
    float* h_sum  = (float*)(ws + off);        off += (size_t)NG * 16 * 4;
    unsigned int* h_max = (unsigned int*)(ws + off); off += (size_t)NG * 16 * 4;
    int* cnt      = (int*)(ws + off);          off += (size_t)NG * 4;
    size_t zero_bytes = off;
    // --- non-zeroed scratch (total ~41 MB) ---
    unsigned int* pack = (unsigned int*)(ws + off); off += (size_t)NB * CAP * 4; // 32 MB
    __half* xh    = (__half*)(ws + off);       off += (size_t)NN * 4 * 2;    // 8 MB

    hipMemsetAsync(d_ws, 0, zero_bytes, stream);

    bin_scatter_k<<<BIN_BLOCKS, 1024, 0, stream>>>(ei, ei + NE, x, binCursor, pack, xh);
    bucket_agg_k<<<NB, 256, 0, stream>>>(pack, binCursor, xh, bat,
                                         w1, b1, w2, b2, h_sum, h_max, cnt);
    out_k<<<(NG + 255) / 256, 256, 0, stream>>>(h_sum, h_max, cnt, w3, b3, out);
}